// Round 6
// baseline (304.980 us; speedup 1.0000x reference)
//
#include <hip/hip_runtime.h>

#define NL   4
#define NH   4
#define HD   64
#define CD   256
#define SQL  1024
#define BB   16

typedef _Float16 half8 __attribute__((ext_vector_type(8)));
typedef _Float16 half4 __attribute__((ext_vector_type(4)));
typedef _Float16 half2v __attribute__((ext_vector_type(2)));
typedef float    f32x4 __attribute__((ext_vector_type(4)));
typedef float    f32x16 __attribute__((ext_vector_type(16)));
typedef unsigned short u16x8 __attribute__((ext_vector_type(8)));
typedef unsigned int  uint4v __attribute__((ext_vector_type(4)));

static __device__ __forceinline__ float bf2f(unsigned short u) {
    union { unsigned int i; float f; } v; v.i = ((unsigned int)u) << 16; return v.f;
}
static __device__ __forceinline__ unsigned short f2bf(float f) {
    union { float f; unsigned int i; } v; v.f = f;
    unsigned int u = v.i;
    return (unsigned short)((u + 0x7fffu + ((u >> 16) & 1u)) >> 16);
}

// inline dtype detect: 1 = inputs are packed bf16, 0 = f32. 16 independent
// dwordx4 loads (R18 fix: was a serial dependent chain).
static __device__ __forceinline__ int detect_flag(const void* win) {
    const uint4v* w = (const uint4v*)win;
    int cnt = 0;
    uint4v u[16];
#pragma unroll
    for (int i = 0; i < 16; i++) u[i] = w[i];
#pragma unroll
    for (int i = 0; i < 16; i++)
#pragma unroll
        for (int j = 0; j < 4; j++) {
            unsigned int lo = u[i][j] & 0xFFFFu;
            int e = (int)((lo >> 7) & 0xFF);
            cnt += (e >= 96 && e <= 144) ? 1 : 0;
        }
    return cnt >= 48 ? 1 : 0;
}

// ---------- merged prep (unchanged from R18) ----------
// x: (B,C,S)->(B,S,C) f16 row-major (gemm B-frags).
// kv: -> kaF / vtF in 32x32x16 MFMA-A-FRAGMENT ORDER: per (layer*NH+h),
//     per 64-l-tile, 8 chunks of [64 entries][8 halfs], glds-compatible.
//     ka chunk c=(lblk,kd16): entry(ln,hi) = K[lblk*32+ln][kd16*16+hi*8+j]
//     vt chunk c=(dblk,ks):   entry(ln,hi) = V[ks*16+hi*8+j][dblk*32+ln]
// w: elementwise cvt. Publishes dtype flag to *flagp.
__global__ __launch_bounds__(256) void prep_all(const void* __restrict__ xin,
                                                const void* __restrict__ win,
                                                const void* __restrict__ kvin,
                                                _Float16* __restrict__ x16,
                                                _Float16* __restrict__ w16,
                                                _Float16* __restrict__ kaF,
                                                _Float16* __restrict__ vtF,
                                                int* __restrict__ flagp) {
    __shared__ __align__(16) _Float16 tile[64][72];
    const int bi = blockIdx.x;
    const int t = threadIdx.x;
    const int isbf = detect_flag(win);

    if (bi < 1024) {
        // ---- prep_x: (B,C,S) -> (B,S,C) f16 ----
        const int st = bi & 15, ct = (bi >> 4) & 3, b = bi >> 6;
        const int r = t >> 2, seg = t & 3;
        const size_t base = ((size_t)(b * CD + ct * 64 + r)) * SQL + st * 64 + seg * 16;
        float v[16];
        if (isbf) {
            const unsigned short* src = (const unsigned short*)xin + base;
            u16x8 u0 = *(const u16x8*)(src);
            u16x8 u1 = *(const u16x8*)(src + 8);
#pragma unroll
            for (int j = 0; j < 8; j++) { v[j] = bf2f(u0[j]); v[8 + j] = bf2f(u1[j]); }
        } else {
            const float* src = (const float*)xin + base;
#pragma unroll
            for (int c = 0; c < 4; c++) {
                f32x4 a = *(const f32x4*)(src + c * 4);
#pragma unroll
                for (int j = 0; j < 4; j++) v[c * 4 + j] = a[j];
            }
        }
#pragma unroll
        for (int j = 0; j < 16; j++) tile[r][seg * 16 + j] = (_Float16)v[j];
        __syncthreads();
        half8 o0, o1;
#pragma unroll
        for (int j = 0; j < 8; j++) { o0[j] = tile[seg * 16 + j][r]; o1[j] = tile[seg * 16 + 8 + j][r]; }
        _Float16* dt = x16 + ((size_t)(b * SQL + st * 64 + r)) * CD + ct * 64 + seg * 16;
        *(half8*)(dt) = o0;
        *(half8*)(dt + 8) = o1;
    } else if (bi < 1280) {
        // ---- prep_kv -> 32x32-fragment-ordered kaF / vtF ----
        const int j2 = bi - 1024;
        const int lt = j2 & 15, ih = j2 >> 4;
        const int r = t >> 2, seg = t & 3;
        const size_t base = ((size_t)(ih * SQL + lt * 64 + r)) * HD + seg * 16;
        float v[16];
        if (isbf) {
            const unsigned short* src = (const unsigned short*)kvin + base;
            u16x8 u0 = *(const u16x8*)(src);
            u16x8 u1 = *(const u16x8*)(src + 8);
#pragma unroll
            for (int j = 0; j < 8; j++) { v[j] = bf2f(u0[j]); v[8 + j] = bf2f(u1[j]); }
        } else {
            const float* src = (const float*)kvin + base;
#pragma unroll
            for (int c = 0; c < 4; c++) {
                f32x4 a = *(const f32x4*)(src + c * 4);
#pragma unroll
                for (int j = 0; j < 4; j++) v[c * 4 + j] = a[j];
            }
        }
#pragma unroll
        for (int j = 0; j < 16; j++) tile[r][seg * 16 + j] = (_Float16)v[j];
        __syncthreads();
        // tile[l_local][d]. Emit 32x32x16 A-frags.
        const int l = t & 63, hie = l >> 5, lne = l & 31;
        _Float16* kaB = kaF + ((size_t)ih << 16);
        _Float16* vtB = vtF + ((size_t)ih << 16);
#pragma unroll
        for (int it = 0; it < 2; it++) {
            const int c = (t >> 6) + it * 4;       // 0..7
            half8 ok = *(const half8*)(&tile[(c >> 2) * 32 + lne][(c & 3) * 16 + hie * 8]);
            half8 ov;
#pragma unroll
            for (int j = 0; j < 8; j++)
                ov[j] = tile[(c & 3) * 16 + hie * 8 + j][(c >> 2) * 32 + lne];
            *(half8*)(kaB + ((lt * 8 + c) << 9) + l * 8) = ok;
            *(half8*)(vtB + ((lt * 8 + c) << 9) + l * 8) = ov;
        }
    } else {
        // ---- prep_w: elementwise cvt (+ flag publish) ----
        if (bi == 1280 && t == 0) *flagp = isbf;
        const int i = (bi - 1280) * 256 + t;
        const size_t base = (size_t)i * 8;
        half8 h;
        if (isbf) {
            u16x8 u = *(const u16x8*)((const unsigned short*)win + base);
#pragma unroll
            for (int j = 0; j < 8; j++) h[j] = (_Float16)bf2f(u[j]);
        } else {
            const float* p = (const float*)win + base;
            f32x4 a0 = *(const f32x4*)(p);
            f32x4 a1 = *(const f32x4*)(p + 4);
#pragma unroll
            for (int j = 0; j < 4; j++) { h[j] = (_Float16)a0[j]; h[4 + j] = (_Float16)a1[j]; }
        }
        *(half8*)(w16 + base) = h;
    }
}

// stage 64-l tile lt into kvbuf[buf][hf]: 8 waves x 2 chunks each (16 chunks:
// c<8 = ka chunk c, c>=8 = vt chunk c-8).
#define STAGE_TILE(kaB_, vtB_, lt_, buf_, hf_)                                         \
    do {                                                                               \
        _Pragma("unroll")                                                              \
        for (int j = 0; j < 2; j++) {                                                  \
            const int c = wv * 2 + j;                                                  \
            const _Float16* src = (c < 8)                                              \
                ? (kaB_) + ((((lt_) * 8 + c) << 9))                                    \
                : (vtB_) + ((((lt_) * 8 + (c - 8)) << 9));                             \
            __builtin_amdgcn_global_load_lds(                                          \
                (const __attribute__((address_space(1))) void*)(src + lane * 8),       \
                (__attribute__((address_space(3))) void*)(&kvbuf[(buf_)][(hf_)][c * 512]), \
                16, 0, 0);                                                             \
        }                                                                              \
    } while (0)

// ---------- fused layer (R20: l-split, 8-wave blocks, 16 waves/CU) ----------
// R19 post-mortem: cooperative launch killed the container (graph-capture
// incompatible) — removed. Accounting fix: the harness's 268MB workspace
// re-poison fill (44 us, visible as fillBufferAligned in every profile) is
// INSIDE the timed window; layers are ~38 us each, floor ~12-20. R15 lesson:
// splitting s across more waves multiplies LDS-read traffic (every wave reads
// the full tile). The free split is L: wave (sg, hl) handles s-group sg's 32
// cols attending to l-half hl's 512 positions — reads only its half's tiles,
// so total LDS traffic is UNCHANGED while waves/CU double to 16 (4/SIMD, 50%
// occupancy) to fill the per-region dep-chain stalls (ds latency, 4-deep MFMA
// chains, exp2) that 2 waves/SIMD left exposed. Softmax is linear pre-norm:
// O = O0+O1, denom = rs0+rs1, combined once via LDS scratch (aliases kvbuf —
// dead after the last region's barrier; stride 37 dwords = conflict-free).
// Cost: q-GEMM computed redundantly by both halves (+11% MFMA). The old A/B
// sub-tile pair becomes the half0/half1 pair: same 64KB LDS, same staging.
__global__ __launch_bounds__(512, 4) void layer_fused(const _Float16* __restrict__ xg,
                                                      _Float16* __restrict__ xout,
                                                      const _Float16* __restrict__ w16,
                                                      const _Float16* __restrict__ kaF,
                                                      const _Float16* __restrict__ vtF,
                                                      const int* __restrict__ flagp,
                                                      void* __restrict__ outp,
                                                      int L) {
    __shared__ __align__(16) _Float16 kvbuf[2][2][8192];  // [buf][l-half][16 chunks x 512]
    const int sb = blockIdx.x;
    const int h  = blockIdx.y;
    const int b  = blockIdx.z;
    const int t  = threadIdx.x;
    const int wv = t >> 6, lane = t & 63, ln = lane & 31, hi = lane >> 5;
    const int sg = wv & 3, hl = wv >> 2;      // s-group, l-half
    const int s0 = sb * 128 + sg * 32;        // wave's 32 s-columns

    const int isbf_final = (L == NL - 1) ? *flagp : 0;

    const _Float16* kaB = kaF + ((size_t)(L * NH + h) << 16);
    const _Float16* vtB = vtF + ((size_t)(L * NH + h) << 16);

    // prologue: half0's tile 0 and half1's tile 8 (overlap the gemm below)
    STAGE_TILE(kaB, vtB, 0, 0, 0);
    STAGE_TILE(kaB, vtB, 8, 0, 1);

    // ---- gemm: q^T[d=64][s=32], 32x32x16 (computed by both l-halves) ----
    f32x16 gacc[2];
#pragma unroll
    for (int dblk = 0; dblk < 2; dblk++)
#pragma unroll
        for (int r = 0; r < 16; r++) gacc[dblk][r] = 0.0f;
    const _Float16* wb = w16 + ((size_t)L << 16) + ((size_t)(h * 64) << 8);
#pragma unroll
    for (int kc = 0; kc < 16; kc++) {
        half8 bx = *(const half8*)(xg + ((size_t)((b << 10) + s0 + ln) << 8) + kc * 16 + hi * 8);
#pragma unroll
        for (int dblk = 0; dblk < 2; dblk++) {
            half8 aw = *(const half8*)(wb + ((size_t)(dblk * 32 + ln) << 8) + kc * 16 + hi * 8);
            gacc[dblk] = __builtin_amdgcn_mfma_f32_32x32x16_f16(aw, bx, gacc[dblk], 0, 0, 0);
        }
    }

    // q C-tile -> QK B-frags (scale 1/8*log2e folded), 8 permlane swaps
    const float sc = 0.180336880111120f;
    half8 qb[4];
#pragma unroll
    for (int dblk = 0; dblk < 2; dblk++)
#pragma unroll
        for (int k1 = 0; k1 < 2; k1++) {
            unsigned int u01 = __builtin_bit_cast(unsigned int,
                __builtin_amdgcn_cvt_pkrtz(gacc[dblk][k1 * 8 + 0] * sc, gacc[dblk][k1 * 8 + 1] * sc));
            unsigned int u23 = __builtin_bit_cast(unsigned int,
                __builtin_amdgcn_cvt_pkrtz(gacc[dblk][k1 * 8 + 2] * sc, gacc[dblk][k1 * 8 + 3] * sc));
            unsigned int w01 = __builtin_bit_cast(unsigned int,
                __builtin_amdgcn_cvt_pkrtz(gacc[dblk][k1 * 8 + 4] * sc, gacc[dblk][k1 * 8 + 5] * sc));
            unsigned int w23 = __builtin_bit_cast(unsigned int,
                __builtin_amdgcn_cvt_pkrtz(gacc[dblk][k1 * 8 + 6] * sc, gacc[dblk][k1 * 8 + 7] * sc));
            asm("v_permlane32_swap_b32 %0, %1" : "+v"(u01), "+v"(w01));
            asm("v_permlane32_swap_b32 %0, %1" : "+v"(u23), "+v"(w23));
            uint4v q; q[0] = u01; q[1] = u23; q[2] = w01; q[3] = w23;
            qb[dblk * 2 + k1] = __builtin_bit_cast(half8, q);
        }

    f32x16 oacc[2];
#pragma unroll
    for (int dblk = 0; dblk < 2; dblk++)
#pragma unroll
        for (int r = 0; r < 16; r++) oacc[dblk][r] = 0.0f;
    f32x4 rsum;
#pragma unroll
    for (int r = 0; r < 4; r++) rsum[r] = 0.0f;

    __syncthreads();   // prologue tiles staged

    // 8 regions; half hl processes tiles hl*8 + ltp
#pragma unroll 1
    for (int ltp = 0; ltp < 8; ltp++) {
        const int buf = ltp & 1;
        if (ltp < 7) {
            STAGE_TILE(kaB, vtB, ltp + 1, buf ^ 1, 0);
            STAGE_TILE(kaB, vtB, 9 + ltp, buf ^ 1, 1);
        }

        const _Float16* base = &kvbuf[buf][hl][0];

        half8 kab[8];
#pragma unroll
        for (int c = 0; c < 8; c++) kab[c] = *(const half8*)(base + c * 512 + lane * 8);

        f32x16 stt[2];
#pragma unroll
        for (int lblk = 0; lblk < 2; lblk++)
#pragma unroll
            for (int r = 0; r < 16; r++) stt[lblk][r] = 0.0f;

        // QK: 2 independent 4-deep chains
        __builtin_amdgcn_s_setprio(1);
#pragma unroll
        for (int lblk = 0; lblk < 2; lblk++)
#pragma unroll
            for (int kd = 0; kd < 4; kd++)
                stt[lblk] = __builtin_amdgcn_mfma_f32_32x32x16_f16(
                    kab[lblk * 4 + kd], qb[kd], stt[lblk], 0, 0, 0);
        __builtin_amdgcn_s_setprio(0);

        half8 vab[8];
#pragma unroll
        for (int c = 0; c < 8; c++) vab[c] = *(const half8*)(base + (8 + c) * 512 + lane * 8);

        // exp2 -> pack -> permlane swap -> P^T B-frags; VALU row-sum
        half8 pb[4];
#pragma unroll
        for (int lblk = 0; lblk < 2; lblk++) {
            float e[16];
#pragma unroll
            for (int r = 0; r < 16; r++) e[r] = __builtin_amdgcn_exp2f(stt[lblk][r]);
#pragma unroll
            for (int g = 0; g < 4; g++)
                rsum[g] += (e[g * 4 + 0] + e[g * 4 + 1]) + (e[g * 4 + 2] + e[g * 4 + 3]);
#pragma unroll
            for (int k1 = 0; k1 < 2; k1++) {
                unsigned int u01 = __builtin_bit_cast(unsigned int,
                    __builtin_amdgcn_cvt_pkrtz(e[k1 * 8 + 0], e[k1 * 8 + 1]));
                unsigned int u23 = __builtin_bit_cast(unsigned int,
                    __builtin_amdgcn_cvt_pkrtz(e[k1 * 8 + 2], e[k1 * 8 + 3]));
                unsigned int w01 = __builtin_bit_cast(unsigned int,
                    __builtin_amdgcn_cvt_pkrtz(e[k1 * 8 + 4], e[k1 * 8 + 5]));
                unsigned int w23 = __builtin_bit_cast(unsigned int,
                    __builtin_amdgcn_cvt_pkrtz(e[k1 * 8 + 6], e[k1 * 8 + 7]));
                asm("v_permlane32_swap_b32 %0, %1" : "+v"(u01), "+v"(w01));
                asm("v_permlane32_swap_b32 %0, %1" : "+v"(u23), "+v"(w23));
                uint4v p; p[0] = u01; p[1] = u23; p[2] = w01; p[3] = w23;
                pb[lblk * 2 + k1] = __builtin_bit_cast(half8, p);
            }
        }

        // PV: 2 independent 4-deep chains
        __builtin_amdgcn_s_setprio(1);
#pragma unroll
        for (int dblk = 0; dblk < 2; dblk++)
#pragma unroll
            for (int ks = 0; ks < 4; ks++)
                oacc[dblk] = __builtin_amdgcn_mfma_f32_32x32x16_f16(
                    vab[dblk * 4 + ks], pb[ks], oacc[dblk], 0, 0, 0);
        __builtin_amdgcn_s_setprio(0);

        __syncthreads();   // drains next-tile glds; protects buf reuse
    }

    // ---- combine l-halves via LDS scratch (aliases kvbuf; safe: all kvbuf
    // reads completed at the last region's barrier, nothing in flight) ----
    float rs = (rsum[0] + rsum[1]) + (rsum[2] + rsum[3]);
    float* scr = (float*)(&kvbuf[0][0][0]);
    const int sidx = (sg * 64 + lane) * 37;   // stride 37: coprime w/ 32 banks

    if (hl == 1) {
#pragma unroll
        for (int dblk = 0; dblk < 2; dblk++)
#pragma unroll
            for (int r = 0; r < 16; r++) scr[sidx + dblk * 16 + r] = oacc[dblk][r];
        scr[sidx + 32] = rs;
    }
    __syncthreads();

    if (hl == 0) {
#pragma unroll
        for (int dblk = 0; dblk < 2; dblk++)
#pragma unroll
            for (int r = 0; r < 16; r++) oacc[dblk][r] += scr[sidx + dblk * 16 + r];
        rs += scr[sidx + 32];

        // denominator: pair-combine own+partner (lane<->lane+32, hi halves)
        unsigned int ra = __builtin_bit_cast(unsigned int, rs);
        unsigned int rb = ra;
        asm("" : "+v"(rb));   // force distinct register lineage
        asm("v_permlane32_swap_b32 %0, %1" : "+v"(ra), "+v"(rb));
        const float inv = 1.0f / (__builtin_bit_cast(float, ra) + __builtin_bit_cast(float, rb));
        const int s = s0 + ln;

        if (L < NL - 1) {
#pragma unroll
            for (int dblk = 0; dblk < 2; dblk++)
#pragma unroll
                for (int q2 = 0; q2 < 4; q2++) {
                    half4 hv;
#pragma unroll
                    for (int r = 0; r < 4; r++) hv[r] = (_Float16)(oacc[dblk][q2 * 4 + r] * inv);
                    *(half4*)(xout + (((size_t)((b << 10) + s)) << 8) +
                              (h << 6) + dblk * 32 + q2 * 8 + hi * 4) = hv;
                }
        } else if (isbf_final) {
#pragma unroll
            for (int dblk = 0; dblk < 2; dblk++)
#pragma unroll
                for (int q2 = 0; q2 < 4; q2++)
#pragma unroll
                    for (int r = 0; r < 4; r++) {
                        const int c = (h << 6) + dblk * 32 + q2 * 8 + hi * 4 + r;
                        ((unsigned short*)outp)[(((size_t)(b * CD + c)) << 10) + s] =
                            f2bf(oacc[dblk][q2 * 4 + r] * inv);
                    }
        } else {
#pragma unroll
            for (int dblk = 0; dblk < 2; dblk++)
#pragma unroll
                for (int q2 = 0; q2 < 4; q2++)
#pragma unroll
                    for (int r = 0; r < 4; r++) {
                        const int c = (h << 6) + dblk * 32 + q2 * 8 + hi * 4 + r;
                        ((float*)outp)[(((size_t)(b * CD + c)) << 10) + s] =
                            oacc[dblk][q2 * 4 + r] * inv;
                    }
        }
    }
}

extern "C" void kernel_launch(void* const* d_in, const int* in_sizes, int n_in,
                              void* d_out, int out_size, void* d_ws, size_t ws_size,
                              hipStream_t stream) {
    const void* xin = d_in[0];
    // d_in[1] = length: used only for its shape (L=1024) — values irrelevant
    const void* win = d_in[2];
    const void* kvin = d_in[3];

    char* ws = (char*)d_ws;
    const size_t MB = 1u << 20;
    _Float16* xa  = (_Float16*)(ws);               // 8 MB  (B,S,C) f16
    _Float16* xb  = (_Float16*)(ws + 8 * MB);      // 8 MB  ping-pong
    _Float16* w16 = (_Float16*)(ws + 16 * MB);     // 0.5 MB
    _Float16* kaF = (_Float16*)(ws + 17 * MB);     // 2 MB  K fragment-order
    _Float16* vtF = (_Float16*)(ws + 19 * MB);     // 2 MB  V^T fragment-order
    int*      flg = (int*)(ws + 21 * MB);          // dtype flag

    prep_all<<<dim3(1024 + 256 + 128), 256, 0, stream>>>(xin, win, kvin, xa, w16, kaF, vtF, flg);

    _Float16* cur = xa;
    _Float16* nxt = xb;
    for (int i = 0; i < NL; i++) {
        layer_fused<<<dim3(SQL / 128, NH, BB), 512, 0, stream>>>(cur, nxt, w16, kaF, vtF,
                                                                 flg, d_out, i);
        _Float16* tmp = cur; cur = nxt; nxt = tmp;
    }
}

// Round 7
// 255.073 us; speedup vs baseline: 1.1957x; 1.1957x over previous
//
#include <hip/hip_runtime.h>

#define NL   4
#define NH   4
#define HD   64
#define CD   256
#define SQL  1024
#define BB   16

typedef _Float16 half8 __attribute__((ext_vector_type(8)));
typedef _Float16 half4 __attribute__((ext_vector_type(4)));
typedef _Float16 half2v __attribute__((ext_vector_type(2)));
typedef float    f32x4 __attribute__((ext_vector_type(4)));
typedef float    f32x16 __attribute__((ext_vector_type(16)));
typedef unsigned short u16x8 __attribute__((ext_vector_type(8)));
typedef unsigned int  uint4v __attribute__((ext_vector_type(4)));

static __device__ __forceinline__ float bf2f(unsigned short u) {
    union { unsigned int i; float f; } v; v.i = ((unsigned int)u) << 16; return v.f;
}
static __device__ __forceinline__ unsigned short f2bf(float f) {
    union { float f; unsigned int i; } v; v.f = f;
    unsigned int u = v.i;
    return (unsigned short)((u + 0x7fffu + ((u >> 16) & 1u)) >> 16);
}

// inline dtype detect: 1 = inputs are packed bf16, 0 = f32. 16 independent
// dwordx4 loads (R18 fix: was a serial dependent chain).
static __device__ __forceinline__ int detect_flag(const void* win) {
    const uint4v* w = (const uint4v*)win;
    int cnt = 0;
    uint4v u[16];
#pragma unroll
    for (int i = 0; i < 16; i++) u[i] = w[i];
#pragma unroll
    for (int i = 0; i < 16; i++)
#pragma unroll
        for (int j = 0; j < 4; j++) {
            unsigned int lo = u[i][j] & 0xFFFFu;
            int e = (int)((lo >> 7) & 0xFF);
            cnt += (e >= 96 && e <= 144) ? 1 : 0;
        }
    return cnt >= 48 ? 1 : 0;
}

// ---------- merged prep (unchanged) ----------
// x: (B,C,S)->(B,S,C) f16 row-major (gemm B-frags).
// kv: -> kaF / vtF in 32x32x16 MFMA-A-FRAGMENT ORDER: per (layer*NH+h),
//     per 64-l-tile, 8 chunks of [64 entries][8 halfs], glds-compatible.
//     ka chunk c=(lblk,kd16): entry(ln,hi) = K[lblk*32+ln][kd16*16+hi*8+j]
//     vt chunk c=(dblk,ks):   entry(ln,hi) = V[ks*16+hi*8+j][dblk*32+ln]
// w: elementwise cvt. Publishes dtype flag to *flagp.
__global__ __launch_bounds__(256) void prep_all(const void* __restrict__ xin,
                                                const void* __restrict__ win,
                                                const void* __restrict__ kvin,
                                                _Float16* __restrict__ x16,
                                                _Float16* __restrict__ w16,
                                                _Float16* __restrict__ kaF,
                                                _Float16* __restrict__ vtF,
                                                int* __restrict__ flagp) {
    __shared__ __align__(16) _Float16 tile[64][72];
    const int bi = blockIdx.x;
    const int t = threadIdx.x;
    const int isbf = detect_flag(win);

    if (bi < 1024) {
        // ---- prep_x: (B,C,S) -> (B,S,C) f16 ----
        const int st = bi & 15, ct = (bi >> 4) & 3, b = bi >> 6;
        const int r = t >> 2, seg = t & 3;
        const size_t base = ((size_t)(b * CD + ct * 64 + r)) * SQL + st * 64 + seg * 16;
        float v[16];
        if (isbf) {
            const unsigned short* src = (const unsigned short*)xin + base;
            u16x8 u0 = *(const u16x8*)(src);
            u16x8 u1 = *(const u16x8*)(src + 8);
#pragma unroll
            for (int j = 0; j < 8; j++) { v[j] = bf2f(u0[j]); v[8 + j] = bf2f(u1[j]); }
        } else {
            const float* src = (const float*)xin + base;
#pragma unroll
            for (int c = 0; c < 4; c++) {
                f32x4 a = *(const f32x4*)(src + c * 4);
#pragma unroll
                for (int j = 0; j < 4; j++) v[c * 4 + j] = a[j];
            }
        }
#pragma unroll
        for (int j = 0; j < 16; j++) tile[r][seg * 16 + j] = (_Float16)v[j];
        __syncthreads();
        half8 o0, o1;
#pragma unroll
        for (int j = 0; j < 8; j++) { o0[j] = tile[seg * 16 + j][r]; o1[j] = tile[seg * 16 + 8 + j][r]; }
        _Float16* dt = x16 + ((size_t)(b * SQL + st * 64 + r)) * CD + ct * 64 + seg * 16;
        *(half8*)(dt) = o0;
        *(half8*)(dt + 8) = o1;
    } else if (bi < 1280) {
        // ---- prep_kv -> 32x32-fragment-ordered kaF / vtF ----
        const int j2 = bi - 1024;
        const int lt = j2 & 15, ih = j2 >> 4;
        const int r = t >> 2, seg = t & 3;
        const size_t base = ((size_t)(ih * SQL + lt * 64 + r)) * HD + seg * 16;
        float v[16];
        if (isbf) {
            const unsigned short* src = (const unsigned short*)kvin + base;
            u16x8 u0 = *(const u16x8*)(src);
            u16x8 u1 = *(const u16x8*)(src + 8);
#pragma unroll
            for (int j = 0; j < 8; j++) { v[j] = bf2f(u0[j]); v[8 + j] = bf2f(u1[j]); }
        } else {
            const float* src = (const float*)kvin + base;
#pragma unroll
            for (int c = 0; c < 4; c++) {
                f32x4 a = *(const f32x4*)(src + c * 4);
#pragma unroll
                for (int j = 0; j < 4; j++) v[c * 4 + j] = a[j];
            }
        }
#pragma unroll
        for (int j = 0; j < 16; j++) tile[r][seg * 16 + j] = (_Float16)v[j];
        __syncthreads();
        // tile[l_local][d]. Emit 32x32x16 A-frags.
        const int l = t & 63, hie = l >> 5, lne = l & 31;
        _Float16* kaB = kaF + ((size_t)ih << 16);
        _Float16* vtB = vtF + ((size_t)ih << 16);
#pragma unroll
        for (int it = 0; it < 2; it++) {
            const int c = (t >> 6) + it * 4;       // 0..7
            half8 ok = *(const half8*)(&tile[(c >> 2) * 32 + lne][(c & 3) * 16 + hie * 8]);
            half8 ov;
#pragma unroll
            for (int j = 0; j < 8; j++)
                ov[j] = tile[(c & 3) * 16 + hie * 8 + j][(c >> 2) * 32 + lne];
            *(half8*)(kaB + ((lt * 8 + c) << 9) + l * 8) = ok;
            *(half8*)(vtB + ((lt * 8 + c) << 9) + l * 8) = ov;
        }
    } else {
        // ---- prep_w: elementwise cvt (+ flag publish) ----
        if (bi == 1280 && t == 0) *flagp = isbf;
        const int i = (bi - 1280) * 256 + t;
        const size_t base = (size_t)i * 8;
        half8 h;
        if (isbf) {
            u16x8 u = *(const u16x8*)((const unsigned short*)win + base);
#pragma unroll
            for (int j = 0; j < 8; j++) h[j] = (_Float16)bf2f(u[j]);
        } else {
            const float* p = (const float*)win + base;
            f32x4 a0 = *(const f32x4*)(p);
            f32x4 a1 = *(const f32x4*)(p + 4);
#pragma unroll
            for (int j = 0; j < 4; j++) { h[j] = (_Float16)a0[j]; h[4 + j] = (_Float16)a1[j]; }
        }
        *(half8*)(w16 + base) = h;
    }
}

// stage 64-l tile lt into kvbuf[buf][hf]: 8 waves x 2 chunks each (16 chunks:
// c<8 = ka chunk c, c>=8 = vt chunk c-8).
#define STAGE_TILE(kaB_, vtB_, lt_, buf_, hf_)                                         \
    do {                                                                               \
        _Pragma("unroll")                                                              \
        for (int j = 0; j < 2; j++) {                                                  \
            const int c = wv * 2 + j;                                                  \
            const _Float16* src = (c < 8)                                              \
                ? (kaB_) + ((((lt_) * 8 + c) << 9))                                    \
                : (vtB_) + ((((lt_) * 8 + (c - 8)) << 9));                             \
            __builtin_amdgcn_global_load_lds(                                          \
                (const __attribute__((address_space(1))) void*)(src + lane * 8),       \
                (__attribute__((address_space(3))) void*)(&kvbuf[(buf_)][(hf_)][c * 512]), \
                16, 0, 0);                                                             \
        }                                                                              \
    } while (0)

// ---------- fused layer (R21: l-split with CORRECT register budget) ----------
// R20 post-mortem: __launch_bounds__(512,4) was interpreted CUDA-style (min
// BLOCKS/CU): 4x8 waves = 8 waves/SIMD -> VGPR capped at 64 (VGPR_Count=64 in
// the profile) vs ~110 live -> massive scratch spills (FETCH 8.7->20.5 MB,
// WRITE 16->33.8 MB = spill traffic, MfmaUtil 12%). The l-split itself was
// never tested. R21 = same structure with (512,2): 2 blocks/CU = 16 waves/CU
// = 4 waves/SIMD, VGPR cap 128. Pressure-shaving reorder: vab LDS loads moved
// AFTER exp/pack (kab+stt dead there) -> peak live ~112 regs; vab latency is
// hidden by the 4-waves/SIMD TLP this config finally provides.
// Structure recap: wave (sg,hl) = s-group sg (32 cols) x l-half hl (512 KV
// positions). Total LDS-read traffic unchanged vs R18 (each wave reads only
// its half's tiles); waves/CU doubled to fill dep-chain stalls. Softmax
// linear pre-norm: O=O0+O1, denom=rs0+rs1 via LDS scratch (aliases kvbuf,
// dead after last barrier; stride 37 = conflict-free). Cost: q-gemm computed
// by both halves (+11% MFMA, +8MB x-fetch ~ 1.3 us HBM).
__global__ __launch_bounds__(512, 2) void layer_fused(const _Float16* __restrict__ xg,
                                                      _Float16* __restrict__ xout,
                                                      const _Float16* __restrict__ w16,
                                                      const _Float16* __restrict__ kaF,
                                                      const _Float16* __restrict__ vtF,
                                                      const int* __restrict__ flagp,
                                                      void* __restrict__ outp,
                                                      int L) {
    __shared__ __align__(16) _Float16 kvbuf[2][2][8192];  // [buf][l-half][16 chunks x 512]
    const int sb = blockIdx.x;
    const int h  = blockIdx.y;
    const int b  = blockIdx.z;
    const int t  = threadIdx.x;
    const int wv = t >> 6, lane = t & 63, ln = lane & 31, hi = lane >> 5;
    const int sg = wv & 3, hl = wv >> 2;      // s-group, l-half
    const int s0 = sb * 128 + sg * 32;        // wave's 32 s-columns

    const int isbf_final = (L == NL - 1) ? *flagp : 0;

    const _Float16* kaB = kaF + ((size_t)(L * NH + h) << 16);
    const _Float16* vtB = vtF + ((size_t)(L * NH + h) << 16);

    // prologue: half0's tile 0 and half1's tile 8 (overlap the gemm below)
    STAGE_TILE(kaB, vtB, 0, 0, 0);
    STAGE_TILE(kaB, vtB, 8, 0, 1);

    // ---- gemm: q^T[d=64][s=32], 32x32x16 (computed by both l-halves) ----
    f32x16 gacc[2];
#pragma unroll
    for (int dblk = 0; dblk < 2; dblk++)
#pragma unroll
        for (int r = 0; r < 16; r++) gacc[dblk][r] = 0.0f;
    const _Float16* wb = w16 + ((size_t)L << 16) + ((size_t)(h * 64) << 8);
#pragma unroll
    for (int kc = 0; kc < 16; kc++) {
        half8 bx = *(const half8*)(xg + ((size_t)((b << 10) + s0 + ln) << 8) + kc * 16 + hi * 8);
#pragma unroll
        for (int dblk = 0; dblk < 2; dblk++) {
            half8 aw = *(const half8*)(wb + ((size_t)(dblk * 32 + ln) << 8) + kc * 16 + hi * 8);
            gacc[dblk] = __builtin_amdgcn_mfma_f32_32x32x16_f16(aw, bx, gacc[dblk], 0, 0, 0);
        }
    }

    // q C-tile -> QK B-frags (scale 1/8*log2e folded), 8 permlane swaps
    const float sc = 0.180336880111120f;
    half8 qb[4];
#pragma unroll
    for (int dblk = 0; dblk < 2; dblk++)
#pragma unroll
        for (int k1 = 0; k1 < 2; k1++) {
            unsigned int u01 = __builtin_bit_cast(unsigned int,
                __builtin_amdgcn_cvt_pkrtz(gacc[dblk][k1 * 8 + 0] * sc, gacc[dblk][k1 * 8 + 1] * sc));
            unsigned int u23 = __builtin_bit_cast(unsigned int,
                __builtin_amdgcn_cvt_pkrtz(gacc[dblk][k1 * 8 + 2] * sc, gacc[dblk][k1 * 8 + 3] * sc));
            unsigned int w01 = __builtin_bit_cast(unsigned int,
                __builtin_amdgcn_cvt_pkrtz(gacc[dblk][k1 * 8 + 4] * sc, gacc[dblk][k1 * 8 + 5] * sc));
            unsigned int w23 = __builtin_bit_cast(unsigned int,
                __builtin_amdgcn_cvt_pkrtz(gacc[dblk][k1 * 8 + 6] * sc, gacc[dblk][k1 * 8 + 7] * sc));
            asm("v_permlane32_swap_b32 %0, %1" : "+v"(u01), "+v"(w01));
            asm("v_permlane32_swap_b32 %0, %1" : "+v"(u23), "+v"(w23));
            uint4v q; q[0] = u01; q[1] = u23; q[2] = w01; q[3] = w23;
            qb[dblk * 2 + k1] = __builtin_bit_cast(half8, q);
        }

    f32x16 oacc[2];
#pragma unroll
    for (int dblk = 0; dblk < 2; dblk++)
#pragma unroll
        for (int r = 0; r < 16; r++) oacc[dblk][r] = 0.0f;
    f32x4 rsum;
#pragma unroll
    for (int r = 0; r < 4; r++) rsum[r] = 0.0f;

    __syncthreads();   // prologue tiles staged

    // 8 regions; half hl processes tiles hl*8 + ltp
#pragma unroll 1
    for (int ltp = 0; ltp < 8; ltp++) {
        const int buf = ltp & 1;
        if (ltp < 7) {
            STAGE_TILE(kaB, vtB, ltp + 1, buf ^ 1, 0);
            STAGE_TILE(kaB, vtB, 9 + ltp, buf ^ 1, 1);
        }

        const _Float16* base = &kvbuf[buf][hl][0];

        half8 kab[8];
#pragma unroll
        for (int c = 0; c < 8; c++) kab[c] = *(const half8*)(base + c * 512 + lane * 8);

        f32x16 stt[2];
#pragma unroll
        for (int lblk = 0; lblk < 2; lblk++)
#pragma unroll
            for (int r = 0; r < 16; r++) stt[lblk][r] = 0.0f;

        // QK: 2 independent 4-deep chains
        __builtin_amdgcn_s_setprio(1);
#pragma unroll
        for (int lblk = 0; lblk < 2; lblk++)
#pragma unroll
            for (int kd = 0; kd < 4; kd++)
                stt[lblk] = __builtin_amdgcn_mfma_f32_32x32x16_f16(
                    kab[lblk * 4 + kd], qb[kd], stt[lblk], 0, 0, 0);
        __builtin_amdgcn_s_setprio(0);

        // exp2 -> pack -> permlane swap -> P^T B-frags; VALU row-sum
        // (vab loads deferred until after: kab+stt dead -> peak ~112 VGPR)
        half8 pb[4];
#pragma unroll
        for (int lblk = 0; lblk < 2; lblk++) {
            float e[16];
#pragma unroll
            for (int r = 0; r < 16; r++) e[r] = __builtin_amdgcn_exp2f(stt[lblk][r]);
#pragma unroll
            for (int g = 0; g < 4; g++)
                rsum[g] += (e[g * 4 + 0] + e[g * 4 + 1]) + (e[g * 4 + 2] + e[g * 4 + 3]);
#pragma unroll
            for (int k1 = 0; k1 < 2; k1++) {
                unsigned int u01 = __builtin_bit_cast(unsigned int,
                    __builtin_amdgcn_cvt_pkrtz(e[k1 * 8 + 0], e[k1 * 8 + 1]));
                unsigned int u23 = __builtin_bit_cast(unsigned int,
                    __builtin_amdgcn_cvt_pkrtz(e[k1 * 8 + 2], e[k1 * 8 + 3]));
                unsigned int w01 = __builtin_bit_cast(unsigned int,
                    __builtin_amdgcn_cvt_pkrtz(e[k1 * 8 + 4], e[k1 * 8 + 5]));
                unsigned int w23 = __builtin_bit_cast(unsigned int,
                    __builtin_amdgcn_cvt_pkrtz(e[k1 * 8 + 6], e[k1 * 8 + 7]));
                asm("v_permlane32_swap_b32 %0, %1" : "+v"(u01), "+v"(w01));
                asm("v_permlane32_swap_b32 %0, %1" : "+v"(u23), "+v"(w23));
                uint4v p; p[0] = u01; p[1] = u23; p[2] = w01; p[3] = w23;
                pb[lblk * 2 + k1] = __builtin_bit_cast(half8, p);
            }
        }

        half8 vab[8];
#pragma unroll
        for (int c = 0; c < 8; c++) vab[c] = *(const half8*)(base + (8 + c) * 512 + lane * 8);

        // PV: 2 independent 4-deep chains
        __builtin_amdgcn_s_setprio(1);
#pragma unroll
        for (int dblk = 0; dblk < 2; dblk++)
#pragma unroll
            for (int ks = 0; ks < 4; ks++)
                oacc[dblk] = __builtin_amdgcn_mfma_f32_32x32x16_f16(
                    vab[dblk * 4 + ks], pb[ks], oacc[dblk], 0, 0, 0);
        __builtin_amdgcn_s_setprio(0);

        __syncthreads();   // drains next-tile glds; protects buf reuse
    }

    // ---- combine l-halves via LDS scratch (aliases kvbuf; safe: all kvbuf
    // reads completed at the last region's barrier, nothing in flight) ----
    float rs = (rsum[0] + rsum[1]) + (rsum[2] + rsum[3]);
    float* scr = (float*)(&kvbuf[0][0][0]);
    const int sidx = (sg * 64 + lane) * 37;   // stride 37: coprime w/ 32 banks

    if (hl == 1) {
#pragma unroll
        for (int dblk = 0; dblk < 2; dblk++)
#pragma unroll
            for (int r = 0; r < 16; r++) scr[sidx + dblk * 16 + r] = oacc[dblk][r];
        scr[sidx + 32] = rs;
    }
    __syncthreads();

    if (hl == 0) {
#pragma unroll
        for (int dblk = 0; dblk < 2; dblk++)
#pragma unroll
            for (int r = 0; r < 16; r++) oacc[dblk][r] += scr[sidx + dblk * 16 + r];
        rs += scr[sidx + 32];

        // denominator: pair-combine own+partner (lane<->lane+32, hi halves)
        unsigned int ra = __builtin_bit_cast(unsigned int, rs);
        unsigned int rb = ra;
        asm("" : "+v"(rb));   // force distinct register lineage
        asm("v_permlane32_swap_b32 %0, %1" : "+v"(ra), "+v"(rb));
        const float inv = 1.0f / (__builtin_bit_cast(float, ra) + __builtin_bit_cast(float, rb));
        const int s = s0 + ln;

        if (L < NL - 1) {
#pragma unroll
            for (int dblk = 0; dblk < 2; dblk++)
#pragma unroll
                for (int q2 = 0; q2 < 4; q2++) {
                    half4 hv;
#pragma unroll
                    for (int r = 0; r < 4; r++) hv[r] = (_Float16)(oacc[dblk][q2 * 4 + r] * inv);
                    *(half4*)(xout + (((size_t)((b << 10) + s)) << 8) +
                              (h << 6) + dblk * 32 + q2 * 8 + hi * 4) = hv;
                }
        } else if (isbf_final) {
#pragma unroll
            for (int dblk = 0; dblk < 2; dblk++)
#pragma unroll
                for (int q2 = 0; q2 < 4; q2++)
#pragma unroll
                    for (int r = 0; r < 4; r++) {
                        const int c = (h << 6) + dblk * 32 + q2 * 8 + hi * 4 + r;
                        ((unsigned short*)outp)[(((size_t)(b * CD + c)) << 10) + s] =
                            f2bf(oacc[dblk][q2 * 4 + r] * inv);
                    }
        } else {
#pragma unroll
            for (int dblk = 0; dblk < 2; dblk++)
#pragma unroll
                for (int q2 = 0; q2 < 4; q2++)
#pragma unroll
                    for (int r = 0; r < 4; r++) {
                        const int c = (h << 6) + dblk * 32 + q2 * 8 + hi * 4 + r;
                        ((float*)outp)[(((size_t)(b * CD + c)) << 10) + s] =
                            oacc[dblk][q2 * 4 + r] * inv;
                    }
        }
    }
}

extern "C" void kernel_launch(void* const* d_in, const int* in_sizes, int n_in,
                              void* d_out, int out_size, void* d_ws, size_t ws_size,
                              hipStream_t stream) {
    const void* xin = d_in[0];
    // d_in[1] = length: used only for its shape (L=1024) — values irrelevant
    const void* win = d_in[2];
    const void* kvin = d_in[3];

    char* ws = (char*)d_ws;
    const size_t MB = 1u << 20;
    _Float16* xa  = (_Float16*)(ws);               // 8 MB  (B,S,C) f16
    _Float16* xb  = (_Float16*)(ws + 8 * MB);      // 8 MB  ping-pong
    _Float16* w16 = (_Float16*)(ws + 16 * MB);     // 0.5 MB
    _Float16* kaF = (_Float16*)(ws + 17 * MB);     // 2 MB  K fragment-order
    _Float16* vtF = (_Float16*)(ws + 19 * MB);     // 2 MB  V^T fragment-order
    int*      flg = (int*)(ws + 21 * MB);          // dtype flag

    prep_all<<<dim3(1024 + 256 + 128), 256, 0, stream>>>(xin, win, kvin, xa, w16, kaF, vtF, flg);

    _Float16* cur = xa;
    _Float16* nxt = xb;
    for (int i = 0; i < NL; i++) {
        layer_fused<<<dim3(SQL / 128, NH, BB), 512, 0, stream>>>(cur, nxt, w16, kaF, vtF,
                                                                 flg, d_out, i);
        _Float16* tmp = cur; cur = nxt; nxt = tmp;
    }
}

// Round 9
// 216.094 us; speedup vs baseline: 1.4113x; 1.1804x over previous
//
#include <hip/hip_runtime.h>

#define NL   4
#define NH   4
#define HD   64
#define CD   256
#define SQL  1024
#define BB   16

typedef _Float16 half8 __attribute__((ext_vector_type(8)));
typedef _Float16 half4 __attribute__((ext_vector_type(4)));
typedef _Float16 half2v __attribute__((ext_vector_type(2)));
typedef float    f32x4 __attribute__((ext_vector_type(4)));
typedef float    f32x16 __attribute__((ext_vector_type(16)));
typedef unsigned short u16x8 __attribute__((ext_vector_type(8)));
typedef unsigned int  uint4v __attribute__((ext_vector_type(4)));

static __device__ __forceinline__ float bf2f(unsigned short u) {
    union { unsigned int i; float f; } v; v.i = ((unsigned int)u) << 16; return v.f;
}
static __device__ __forceinline__ unsigned short f2bf(float f) {
    union { float f; unsigned int i; } v; v.f = f;
    unsigned int u = v.i;
    return (unsigned short)((u + 0x7fffu + ((u >> 16) & 1u)) >> 16);
}

// inline dtype detect: 1 = inputs are packed bf16, 0 = f32. 16 independent
// dwordx4 loads (R18 fix: was a serial dependent chain).
static __device__ __forceinline__ int detect_flag(const void* win) {
    const uint4v* w = (const uint4v*)win;
    int cnt = 0;
    uint4v u[16];
#pragma unroll
    for (int i = 0; i < 16; i++) u[i] = w[i];
#pragma unroll
    for (int i = 0; i < 16; i++)
#pragma unroll
        for (int j = 0; j < 4; j++) {
            unsigned int lo = u[i][j] & 0xFFFFu;
            int e = (int)((lo >> 7) & 0xFF);
            cnt += (e >= 96 && e <= 144) ? 1 : 0;
        }
    return cnt >= 48 ? 1 : 0;
}

// ---------- merged prep (unchanged) ----------
// x: (B,C,S)->(B,S,C) f16 row-major (gemm B-frags).
// kv: -> kaF / vtF in 32x32x16 MFMA-A-FRAGMENT ORDER: per (layer*NH+h),
//     per 64-l-tile, 8 chunks of [64 entries][8 halfs]. Each chunk is 1KB
//     with entry = lane*16B: a perfectly coalesced global_load_dwordx4.
//     ka chunk c=(lblk,kd16): entry(ln,hi) = K[lblk*32+ln][kd16*16+hi*8+j]
//     vt chunk c=(dblk,ks):   entry(ln,hi) = V[ks*16+hi*8+j][dblk*32+ln]
// w: elementwise cvt. Publishes dtype flag to *flagp.
__global__ __launch_bounds__(256) void prep_all(const void* __restrict__ xin,
                                                const void* __restrict__ win,
                                                const void* __restrict__ kvin,
                                                _Float16* __restrict__ x16,
                                                _Float16* __restrict__ w16,
                                                _Float16* __restrict__ kaF,
                                                _Float16* __restrict__ vtF,
                                                int* __restrict__ flagp) {
    __shared__ __align__(16) _Float16 tile[64][72];
    const int bi = blockIdx.x;
    const int t = threadIdx.x;
    const int isbf = detect_flag(win);

    if (bi < 1024) {
        // ---- prep_x: (B,C,S) -> (B,S,C) f16 ----
        const int st = bi & 15, ct = (bi >> 4) & 3, b = bi >> 6;
        const int r = t >> 2, seg = t & 3;
        const size_t base = ((size_t)(b * CD + ct * 64 + r)) * SQL + st * 64 + seg * 16;
        float v[16];
        if (isbf) {
            const unsigned short* src = (const unsigned short*)xin + base;
            u16x8 u0 = *(const u16x8*)(src);
            u16x8 u1 = *(const u16x8*)(src + 8);
#pragma unroll
            for (int j = 0; j < 8; j++) { v[j] = bf2f(u0[j]); v[8 + j] = bf2f(u1[j]); }
        } else {
            const float* src = (const float*)xin + base;
#pragma unroll
            for (int c = 0; c < 4; c++) {
                f32x4 a = *(const f32x4*)(src + c * 4);
#pragma unroll
                for (int j = 0; j < 4; j++) v[c * 4 + j] = a[j];
            }
        }
#pragma unroll
        for (int j = 0; j < 16; j++) tile[r][seg * 16 + j] = (_Float16)v[j];
        __syncthreads();
        half8 o0, o1;
#pragma unroll
        for (int j = 0; j < 8; j++) { o0[j] = tile[seg * 16 + j][r]; o1[j] = tile[seg * 16 + 8 + j][r]; }
        _Float16* dt = x16 + ((size_t)(b * SQL + st * 64 + r)) * CD + ct * 64 + seg * 16;
        *(half8*)(dt) = o0;
        *(half8*)(dt + 8) = o1;
    } else if (bi < 1280) {
        // ---- prep_kv -> 32x32-fragment-ordered kaF / vtF ----
        const int j2 = bi - 1024;
        const int lt = j2 & 15, ih = j2 >> 4;
        const int r = t >> 2, seg = t & 3;
        const size_t base = ((size_t)(ih * SQL + lt * 64 + r)) * HD + seg * 16;
        float v[16];
        if (isbf) {
            const unsigned short* src = (const unsigned short*)kvin + base;
            u16x8 u0 = *(const u16x8*)(src);
            u16x8 u1 = *(const u16x8*)(src + 8);
#pragma unroll
            for (int j = 0; j < 8; j++) { v[j] = bf2f(u0[j]); v[8 + j] = bf2f(u1[j]); }
        } else {
            const float* src = (const float*)kvin + base;
#pragma unroll
            for (int c = 0; c < 4; c++) {
                f32x4 a = *(const f32x4*)(src + c * 4);
#pragma unroll
                for (int j = 0; j < 4; j++) v[c * 4 + j] = a[j];
            }
        }
#pragma unroll
        for (int j = 0; j < 16; j++) tile[r][seg * 16 + j] = (_Float16)v[j];
        __syncthreads();
        // tile[l_local][d]. Emit 32x32x16 A-frags.
        const int l = t & 63, hie = l >> 5, lne = l & 31;
        _Float16* kaB = kaF + ((size_t)ih << 16);
        _Float16* vtB = vtF + ((size_t)ih << 16);
#pragma unroll
        for (int it = 0; it < 2; it++) {
            const int c = (t >> 6) + it * 4;       // 0..7
            half8 ok = *(const half8*)(&tile[(c >> 2) * 32 + lne][(c & 3) * 16 + hie * 8]);
            half8 ov;
#pragma unroll
            for (int j = 0; j < 8; j++)
                ov[j] = tile[(c & 3) * 16 + hie * 8 + j][(c >> 2) * 32 + lne];
            *(half8*)(kaB + ((lt * 8 + c) << 9) + l * 8) = ok;
            *(half8*)(vtB + ((lt * 8 + c) << 9) + l * 8) = ov;
        }
    } else {
        // ---- prep_w: elementwise cvt (+ flag publish) ----
        if (bi == 1280 && t == 0) *flagp = isbf;
        const int i = (bi - 1280) * 256 + t;
        const size_t base = (size_t)i * 8;
        half8 h;
        if (isbf) {
            u16x8 u = *(const u16x8*)((const unsigned short*)win + base);
#pragma unroll
            for (int j = 0; j < 8; j++) h[j] = (_Float16)bf2f(u[j]);
        } else {
            const float* p = (const float*)win + base;
            f32x4 a0 = *(const f32x4*)(p);
            f32x4 a1 = *(const f32x4*)(p + 4);
#pragma unroll
            for (int j = 0; j < 4; j++) { h[j] = (_Float16)a0[j]; h[4 + j] = (_Float16)a1[j]; }
        }
        *(half8*)(w16 + base) = h;
    }
}

// ---------- fused layer (R23 = R22 rerun: barrier-free direct-global) ----------
// R22 got no data (container failed twice). Source audit found no possible
// GPU fault: K/V max offset 65528 halfs < 65536/block, x max offset = exactly
// the 8MB allocation, no barriers/LDS/coop-launch/deadlock paths. Failure
// attributed to broker/container flakiness -> rerun unchanged (changing the
// design would conflate infra-flake with theory-test).
// Design recap (R21 falsified LDS-BW theory: halving LDS traffic with clean
// regs REGRESSED): every 64KB-LDS variant ran ~1 resident block/CU, grid =
// ~2 sequential generations of per-block serial time, per-region barriers
// lockstep the few resident waves. R23 deletes the cause: NO LDS, NO
// barriers. kaF/vtF chunks are per-lane coalesced (chunk + lane*16B =
// global_load_dwordx4); each wave independently streams its 16 K/V tiles:
//   - K double-buffered (ka0/ka1): tile t+1 issued before processing t
//   - V issued BEFORE QK: L2 latency (~200-300cy) hides under QK+exp
//   - 4 waves/block hit the same lines -> L1 reuse; KV (256KB) L2-resident
// LDS=0, VGPR ~230 -> 8 waves/CU co-resident with nothing to wait on.
// Body = R18's proven tile body (32x32x16 MFMA, exp2 w/ log2e in q scale,
// cvt_pkrtz+permlane32_swap C->B). Decision rules: 3rd container failure =>
// kernel is the killer, revert to R18 + offline compile analysis; runs but
// >=35us/layer => VALU/exp chain is the wall, move row-sum to MFMA pipe.
__global__ __launch_bounds__(256) void layer_fused(const _Float16* __restrict__ xg,
                                                   _Float16* __restrict__ xout,
                                                   const _Float16* __restrict__ w16,
                                                   const _Float16* __restrict__ kaF,
                                                   const _Float16* __restrict__ vtF,
                                                   const int* __restrict__ flagp,
                                                   void* __restrict__ outp,
                                                   int L) {
    const int sb = blockIdx.x;
    const int h  = blockIdx.y;
    const int b  = blockIdx.z;
    const int t  = threadIdx.x;
    const int wv = t >> 6, lane = t & 63, ln = lane & 31, hi = lane >> 5;
    const int s0 = sb * 128 + wv * 32;        // wave's 32 s-columns

    const int isbf_final = (L == NL - 1) ? *flagp : 0;

    const _Float16* kaB = kaF + ((size_t)(L * NH + h) << 16) + lane * 8;
    const _Float16* vtB = vtF + ((size_t)(L * NH + h) << 16) + lane * 8;

    // ---- gemm: q^T[d=64][s=32], 32x32x16, M=d 2x32, N=s=32, K=c 16x16 ----
    f32x16 gacc[2];
#pragma unroll
    for (int dblk = 0; dblk < 2; dblk++)
#pragma unroll
        for (int r = 0; r < 16; r++) gacc[dblk][r] = 0.0f;
    const _Float16* wb = w16 + ((size_t)L << 16) + ((size_t)(h * 64) << 8);
#pragma unroll
    for (int kc = 0; kc < 16; kc++) {
        half8 bx = *(const half8*)(xg + ((size_t)((b << 10) + s0 + ln) << 8) + kc * 16 + hi * 8);
#pragma unroll
        for (int dblk = 0; dblk < 2; dblk++) {
            half8 aw = *(const half8*)(wb + ((size_t)(dblk * 32 + ln) << 8) + kc * 16 + hi * 8);
            gacc[dblk] = __builtin_amdgcn_mfma_f32_32x32x16_f16(aw, bx, gacc[dblk], 0, 0, 0);
        }
    }

    // q C-tile -> QK B-frags (scale 1/8*log2e folded), 8 permlane swaps
    const float sc = 0.180336880111120f;
    half8 qb[4];
#pragma unroll
    for (int dblk = 0; dblk < 2; dblk++)
#pragma unroll
        for (int k1 = 0; k1 < 2; k1++) {
            unsigned int u01 = __builtin_bit_cast(unsigned int,
                __builtin_amdgcn_cvt_pkrtz(gacc[dblk][k1 * 8 + 0] * sc, gacc[dblk][k1 * 8 + 1] * sc));
            unsigned int u23 = __builtin_bit_cast(unsigned int,
                __builtin_amdgcn_cvt_pkrtz(gacc[dblk][k1 * 8 + 2] * sc, gacc[dblk][k1 * 8 + 3] * sc));
            unsigned int w01 = __builtin_bit_cast(unsigned int,
                __builtin_amdgcn_cvt_pkrtz(gacc[dblk][k1 * 8 + 4] * sc, gacc[dblk][k1 * 8 + 5] * sc));
            unsigned int w23 = __builtin_bit_cast(unsigned int,
                __builtin_amdgcn_cvt_pkrtz(gacc[dblk][k1 * 8 + 6] * sc, gacc[dblk][k1 * 8 + 7] * sc));
            asm("v_permlane32_swap_b32 %0, %1" : "+v"(u01), "+v"(w01));
            asm("v_permlane32_swap_b32 %0, %1" : "+v"(u23), "+v"(w23));
            uint4v q; q[0] = u01; q[1] = u23; q[2] = w01; q[3] = w23;
            qb[dblk * 2 + k1] = __builtin_bit_cast(half8, q);
        }

    f32x16 oacc[2];
#pragma unroll
    for (int dblk = 0; dblk < 2; dblk++)
#pragma unroll
        for (int r = 0; r < 16; r++) oacc[dblk][r] = 0.0f;
    f32x4 rsum;
#pragma unroll
    for (int r = 0; r < 4; r++) rsum[r] = 0.0f;

    // per-tile compute: QK -> exp/pack/swap -> PV (R18 body, registers only)
    auto process = [&](const half8* ka, const half8* va) {
        f32x16 stt[2];
#pragma unroll
        for (int lblk = 0; lblk < 2; lblk++)
#pragma unroll
            for (int r = 0; r < 16; r++) stt[lblk][r] = 0.0f;
        __builtin_amdgcn_s_setprio(1);
#pragma unroll
        for (int lblk = 0; lblk < 2; lblk++)
#pragma unroll
            for (int kd = 0; kd < 4; kd++)
                stt[lblk] = __builtin_amdgcn_mfma_f32_32x32x16_f16(
                    ka[lblk * 4 + kd], qb[kd], stt[lblk], 0, 0, 0);
        __builtin_amdgcn_s_setprio(0);

        half8 pb[4];
#pragma unroll
        for (int lblk = 0; lblk < 2; lblk++) {
            float e[16];
#pragma unroll
            for (int r = 0; r < 16; r++) e[r] = __builtin_amdgcn_exp2f(stt[lblk][r]);
#pragma unroll
            for (int g = 0; g < 4; g++)
                rsum[g] += (e[g * 4 + 0] + e[g * 4 + 1]) + (e[g * 4 + 2] + e[g * 4 + 3]);
#pragma unroll
            for (int k1 = 0; k1 < 2; k1++) {
                unsigned int u01 = __builtin_bit_cast(unsigned int,
                    __builtin_amdgcn_cvt_pkrtz(e[k1 * 8 + 0], e[k1 * 8 + 1]));
                unsigned int u23 = __builtin_bit_cast(unsigned int,
                    __builtin_amdgcn_cvt_pkrtz(e[k1 * 8 + 2], e[k1 * 8 + 3]));
                unsigned int w01 = __builtin_bit_cast(unsigned int,
                    __builtin_amdgcn_cvt_pkrtz(e[k1 * 8 + 4], e[k1 * 8 + 5]));
                unsigned int w23 = __builtin_bit_cast(unsigned int,
                    __builtin_amdgcn_cvt_pkrtz(e[k1 * 8 + 6], e[k1 * 8 + 7]));
                asm("v_permlane32_swap_b32 %0, %1" : "+v"(u01), "+v"(w01));
                asm("v_permlane32_swap_b32 %0, %1" : "+v"(u23), "+v"(w23));
                uint4v p; p[0] = u01; p[1] = u23; p[2] = w01; p[3] = w23;
                pb[lblk * 2 + k1] = __builtin_bit_cast(half8, p);
            }
        }

        __builtin_amdgcn_s_setprio(1);
#pragma unroll
        for (int dblk = 0; dblk < 2; dblk++)
#pragma unroll
            for (int ks = 0; ks < 4; ks++)
                oacc[dblk] = __builtin_amdgcn_mfma_f32_32x32x16_f16(
                    va[dblk * 4 + ks], pb[ks], oacc[dblk], 0, 0, 0);
        __builtin_amdgcn_s_setprio(0);
    };

#define LOADK(dst, lt)                                                        \
    do {                                                                      \
        _Pragma("unroll")                                                     \
        for (int c = 0; c < 8; c++)                                           \
            dst[c] = *(const half8*)(kaB + (((lt) * 8 + c) << 9));            \
    } while (0)
#define LOADV(dst, lt)                                                        \
    do {                                                                      \
        _Pragma("unroll")                                                     \
        for (int c = 0; c < 8; c++)                                           \
            dst[c] = *(const half8*)(vtB + (((lt) * 8 + c) << 9));            \
    } while (0)

    half8 ka0[8], ka1[8], va[8];
    LOADK(ka0, 0);
    LOADV(va, 0);                 // iteration 0's V latency also pre-covered

#pragma unroll 1
    for (int lt = 0; lt < 16; lt += 2) {
        LOADK(ka1, lt + 1);       // K(t+1): covered by all of tile t
        process(ka0, va);
        LOADV(va, lt + 1);        // V(t+1): covered by... (issued just before use window)
        if (lt + 2 < 16) LOADK(ka0, lt + 2);
        process(ka1, va);
        if (lt + 2 < 16) LOADV(va, lt + 2);
    }
#undef LOADK
#undef LOADV

    // ---- denominator: pair-combine own+partner (lane<->lane+32) ----
    float rs = (rsum[0] + rsum[1]) + (rsum[2] + rsum[3]);
    unsigned int ra = __builtin_bit_cast(unsigned int, rs);
    unsigned int rb = ra;
    asm("" : "+v"(rb));   // force distinct register lineage
    asm("v_permlane32_swap_b32 %0, %1" : "+v"(ra), "+v"(rb));
    const float inv = 1.0f / (__builtin_bit_cast(float, ra) + __builtin_bit_cast(float, rb));
    const int s = s0 + ln;

    if (L < NL - 1) {
#pragma unroll
        for (int dblk = 0; dblk < 2; dblk++)
#pragma unroll
            for (int q2 = 0; q2 < 4; q2++) {
                half4 hv;
#pragma unroll
                for (int r = 0; r < 4; r++) hv[r] = (_Float16)(oacc[dblk][q2 * 4 + r] * inv);
                *(half4*)(xout + (((size_t)((b << 10) + s)) << 8) +
                          (h << 6) + dblk * 32 + q2 * 8 + hi * 4) = hv;
            }
    } else if (isbf_final) {
#pragma unroll
        for (int dblk = 0; dblk < 2; dblk++)
#pragma unroll
            for (int q2 = 0; q2 < 4; q2++)
#pragma unroll
                for (int r = 0; r < 4; r++) {
                    const int c = (h << 6) + dblk * 32 + q2 * 8 + hi * 4 + r;
                    ((unsigned short*)outp)[(((size_t)(b * CD + c)) << 10) + s] =
                        f2bf(oacc[dblk][q2 * 4 + r] * inv);
                }
    } else {
#pragma unroll
        for (int dblk = 0; dblk < 2; dblk++)
#pragma unroll
            for (int q2 = 0; q2 < 4; q2++)
#pragma unroll
                for (int r = 0; r < 4; r++) {
                    const int c = (h << 6) + dblk * 32 + q2 * 8 + hi * 4 + r;
                    ((float*)outp)[(((size_t)(b * CD + c)) << 10) + s] =
                        oacc[dblk][q2 * 4 + r] * inv;
                }
    }
}

extern "C" void kernel_launch(void* const* d_in, const int* in_sizes, int n_in,
                              void* d_out, int out_size, void* d_ws, size_t ws_size,
                              hipStream_t stream) {
    const void* xin = d_in[0];
    // d_in[1] = length: used only for its shape (L=1024) — values irrelevant
    const void* win = d_in[2];
    const void* kvin = d_in[3];

    char* ws = (char*)d_ws;
    const size_t MB = 1u << 20;
    _Float16* xa  = (_Float16*)(ws);               // 8 MB  (B,S,C) f16
    _Float16* xb  = (_Float16*)(ws + 8 * MB);      // 8 MB  ping-pong
    _Float16* w16 = (_Float16*)(ws + 16 * MB);     // 0.5 MB
    _Float16* kaF = (_Float16*)(ws + 17 * MB);     // 2 MB  K fragment-order
    _Float16* vtF = (_Float16*)(ws + 19 * MB);     // 2 MB  V^T fragment-order
    int*      flg = (int*)(ws + 21 * MB);          // dtype flag

    prep_all<<<dim3(1024 + 256 + 128), 256, 0, stream>>>(xin, win, kvin, xa, w16, kaF, vtF, flg);

    _Float16* cur = xa;
    _Float16* nxt = xb;
    for (int i = 0; i < NL; i++) {
        layer_fused<<<dim3(SQL / 128, NH, BB), 256, 0, stream>>>(cur, nxt, w16, kaF, vtF,
                                                                 flg, d_out, i);
        _Float16* tmp = cur; cur = nxt; nxt = tmp;
    }
}